// Round 1
// baseline (132.773 us; speedup 1.0000x reference)
//
#include <hip/hip_runtime.h>
#include <math.h>

#define NCV   30000
#define NX    60000
#define NM    8
#define LN_EPSF 1e-5f

// ---------------- workspace layout (float offsets) ----------------
#define WS_XRAW   0          // 60000  (cos | sin)
#define WS_Y      60000      // 60000  post-LN MLP input
#define WS_DCV    120000     // 360000 dphi/dx (30000 x 12)
#define WS_G      480000     // 480000 dE/dxhat per model (8 x 60000)
#define WS_MF     960000     // 30000  mean force per CV
#define WS_Z0     990000     // 512
#define WS_DZ0    990512     // 512
#define WS_E      991024     // 8
#define WS_SUMS   991032     // 2 (sum x, sum x^2)
#define WS_SG     991040     // 8
#define WS_SGX    991048     // 8
#define WS_VARSUM 991056     // 1
#define WS_SIGMA  991057     // 1
#define WS_TOTAL  991058

struct F3 { float x, y, z; };
__device__ __forceinline__ F3 f3sub(F3 a, F3 b){ return {a.x-b.x, a.y-b.y, a.z-b.z}; }
__device__ __forceinline__ F3 f3add(F3 a, F3 b){ return {a.x+b.x, a.y+b.y, a.z+b.z}; }
__device__ __forceinline__ F3 f3scale(F3 a, float s){ return {a.x*s, a.y*s, a.z*s}; }
__device__ __forceinline__ float f3dot(F3 a, F3 b){ return a.x*b.x + a.y*b.y + a.z*b.z; }
__device__ __forceinline__ F3 f3cross(F3 a, F3 b){
  return { a.y*b.z - a.z*b.y, a.z*b.x - a.x*b.z, a.x*b.y - a.y*b.x };
}

__device__ __forceinline__ void block_sum2(float a, float b, float* out0, float* out1) {
  #pragma unroll
  for (int o = 1; o < 64; o <<= 1) { a += __shfl_xor(a, o); b += __shfl_xor(b, o); }
  __shared__ float sa[4], sb[4];
  int w = threadIdx.x >> 6, l = threadIdx.x & 63;
  if (l == 0) { sa[w] = a; sb[w] = b; }
  __syncthreads();
  if (threadIdx.x == 0) {
    int nw = (blockDim.x + 63) >> 6;
    float A = 0.f, B = 0.f;
    for (int t = 0; t < nw; t++) { A += sa[t]; B += sb[t]; }
    atomicAdd(out0, A); atomicAdd(out1, B);
  }
}

__device__ __forceinline__ void block_sum1(float a, float* out0) {
  #pragma unroll
  for (int o = 1; o < 64; o <<= 1) a += __shfl_xor(a, o);
  __shared__ float sa[4];
  int w = threadIdx.x >> 6, l = threadIdx.x & 63;
  if (l == 0) sa[w] = a;
  __syncthreads();
  if (threadIdx.x == 0) {
    int nw = (blockDim.x + 63) >> 6;
    float A = 0.f;
    for (int t = 0; t < nw; t++) A += sa[t];
    atomicAdd(out0, A);
  }
}

// ---------------- K1: dihedrals + grads + LN stats ----------------
__global__ void k_cv(const float* __restrict__ pos, const float* __restrict__ box,
                     const int* __restrict__ idx, float* __restrict__ ws) {
  int i = blockIdx.x * blockDim.x + threadIdx.x;
  float cx = 0.f, cx2 = 0.f;
  if (i < NCV) {
    float bx = box[0], by = box[4], bz = box[8];
    F3 p[4];
    #pragma unroll
    for (int a = 0; a < 4; a++) {
      int pi = idx[i*4 + a];
      float X = pos[(size_t)pi*3 + 0];
      float Y = pos[(size_t)pi*3 + 1];
      float Z = pos[(size_t)pi*3 + 2];
      X -= floorf(X / bx) * bx;
      Y -= floorf(Y / by) * by;
      Z -= floorf(Z / bz) * bz;
      p[a] = {X, Y, Z};
    }
    F3 b1 = f3sub(p[1], p[0]);
    F3 b2 = f3sub(p[2], p[1]);
    F3 b3 = f3sub(p[3], p[2]);
    F3 n1 = f3cross(b1, b2);
    F3 n2 = f3cross(b2, b3);
    float L = sqrtf(f3dot(b2, b2));
    F3 u = f3scale(b2, 1.f / L);
    F3 m1 = f3cross(n1, u);
    float yv = f3dot(m1, n2);
    float xv = f3dot(n1, n2);
    float h = sqrtf(xv*xv + yv*yv);
    float cphi = xv / h;
    float sphi = yv / h;

    // reverse mode, dphi = 1
    float invd = 1.f / (h*h);
    float dX = -yv * invd;       // d/dx of atan2(y,x)
    float dY =  xv * invd;       // d/dy
    F3 dn1 = f3scale(n2, dX);
    F3 dn2 = f3scale(n1, dX);
    F3 dm1 = f3scale(n2, dY);
    dn2 = f3add(dn2, f3scale(m1, dY));
    // m1 = n1 x u
    dn1 = f3add(dn1, f3cross(u, dm1));
    F3 du = f3cross(dm1, n1);
    // u = b2 / L
    float ud = f3dot(u, du);
    F3 db2 = f3scale(f3sub(du, f3scale(u, ud)), 1.f / L);
    // n2 = b2 x b3
    db2 = f3add(db2, f3cross(b3, dn2));
    F3 db3 = f3cross(dn2, b2);
    // n1 = b1 x b2
    F3 db1 = f3cross(b2, dn1);
    db2 = f3add(db2, f3cross(dn1, b1));

    F3 g0 = f3scale(db1, -1.f);
    F3 g1 = f3sub(db1, db2);
    F3 g2 = f3sub(db2, db3);
    F3 g3 = db3;

    ws[WS_XRAW + i]       = cphi;
    ws[WS_XRAW + NCV + i] = sphi;
    float* dc = ws + WS_DCV + (size_t)i * 12;
    dc[0] = g0.x; dc[1]  = g0.y; dc[2]  = g0.z;
    dc[3] = g1.x; dc[4]  = g1.y; dc[5]  = g1.z;
    dc[6] = g2.x; dc[7]  = g2.y; dc[8]  = g2.z;
    dc[9] = g3.x; dc[10] = g3.y; dc[11] = g3.z;

    cx  = cphi + sphi;
    cx2 = cphi*cphi + sphi*sphi;
  }
  block_sum2(cx, cx2, ws + WS_SUMS + 0, ws + WS_SUMS + 1);
}

// ---------------- K2: layernorm -> y ----------------
__global__ void k_y(const float* __restrict__ gamma, const float* __restrict__ beta,
                    float* __restrict__ ws) {
  int j = blockIdx.x * blockDim.x + threadIdx.x;
  if (j >= NX) return;
  float mu  = ws[WS_SUMS + 0] * (1.f / NX);
  float var = ws[WS_SUMS + 1] * (1.f / NX) - mu * mu;
  float inv = 1.f / sqrtf(var + LN_EPSF);
  float xh = (ws[WS_XRAW + j] - mu) * inv;
  ws[WS_Y + j] = xh * gamma[j] + beta[j];
}

// ---------------- K3: z0[m][k] = sum_j y[j] W0[m][j][k] ----------------
__global__ void k_z0(const float4* __restrict__ W0, const float* __restrict__ yv,
                     float* __restrict__ z0) {
  int m  = blockIdx.y;
  int k4 = threadIdx.x & 15;   // which float4 of the 64-wide row
  int r  = threadIdx.x >> 4;   // row phase 0..15
  int j0 = blockIdx.x * 1024;
  int jend = min(j0 + 1024, NX);
  const float4* Wm = W0 + (size_t)m * NX * 16;
  float4 acc = {0.f, 0.f, 0.f, 0.f};
  for (int j = j0 + r; j < jend; j += 16) {
    float y = yv[j];
    float4 wv = Wm[(size_t)j * 16 + k4];
    acc.x += y * wv.x; acc.y += y * wv.y; acc.z += y * wv.z; acc.w += y * wv.w;
  }
  // lanes l, l^16, l^32, l^48 share k4 -> reduce within wave
  #pragma unroll
  for (int o = 16; o <= 32; o <<= 1) {
    acc.x += __shfl_xor(acc.x, o); acc.y += __shfl_xor(acc.y, o);
    acc.z += __shfl_xor(acc.z, o); acc.w += __shfl_xor(acc.w, o);
  }
  __shared__ float red[4][16][4];
  int w = threadIdx.x >> 6, l = threadIdx.x & 63;
  if (l < 16) {
    red[w][l][0] = acc.x; red[w][l][1] = acc.y; red[w][l][2] = acc.z; red[w][l][3] = acc.w;
  }
  __syncthreads();
  if (threadIdx.x < 64) {
    int kk4 = threadIdx.x & 15, c = threadIdx.x >> 4;
    float v = red[0][kk4][c] + red[1][kk4][c] + red[2][kk4][c] + red[3][kk4][c];
    atomicAdd(&z0[m * 64 + kk4 * 4 + c], v);
  }
}

// ---------------- K4: tiny MLP fwd+bwd per model ----------------
__global__ void k_mlp(const float* __restrict__ z0, const float* __restrict__ b0,
                      const float* __restrict__ W1, const float* __restrict__ b1,
                      const float* __restrict__ W2, const float* __restrict__ b2,
                      const float* __restrict__ W3, const float* __restrict__ b3,
                      const float* __restrict__ W4, const float* __restrict__ b4,
                      float* __restrict__ dz0, float* __restrict__ E) {
  int m = blockIdx.x, k = threadIdx.x;   // 64 threads
  __shared__ float h0[64], h1[64], h2[64], d3[64], d2[64], d1[64];
  const float* W1m = W1 + m * 4096;
  const float* W2m = W2 + m * 4096;
  const float* W3m = W3 + m * 4096;

  float a0 = z0[m*64 + k] + b0[m*64 + k];
  h0[k] = fmaxf(a0, 0.f);
  __syncthreads();
  float a1 = b1[m*64 + k];
  #pragma unroll 8
  for (int t = 0; t < 64; t++) a1 += h0[t] * W1m[t*64 + k];
  h1[k] = fmaxf(a1, 0.f);
  __syncthreads();
  float a2 = b2[m*64 + k];
  #pragma unroll 8
  for (int t = 0; t < 64; t++) a2 += h1[t] * W2m[t*64 + k];
  h2[k] = fmaxf(a2, 0.f);
  __syncthreads();
  float a3 = b3[m*64 + k];
  #pragma unroll 8
  for (int t = 0; t < 64; t++) a3 += h2[t] * W3m[t*64 + k];
  float h3 = fmaxf(a3, 0.f);

  float w4 = W4[m*64 + k];
  float e = h3 * w4;
  #pragma unroll
  for (int o = 1; o < 64; o <<= 1) e += __shfl_xor(e, o);
  if (k == 0) E[m] = e + b4[m];

  // backward
  float dz3 = (a3 > 0.f) ? w4 : 0.f;
  d3[k] = dz3;
  __syncthreads();
  float dh2 = 0.f;
  #pragma unroll 8
  for (int t = 0; t < 64; t++) dh2 += W3m[k*64 + t] * d3[t];
  float dz2 = (a2 > 0.f) ? dh2 : 0.f;
  d2[k] = dz2;
  __syncthreads();
  float dh1 = 0.f;
  #pragma unroll 8
  for (int t = 0; t < 64; t++) dh1 += W2m[k*64 + t] * d2[t];
  float dz1 = (a1 > 0.f) ? dh1 : 0.f;
  d1[k] = dz1;
  __syncthreads();
  float dh0 = 0.f;
  #pragma unroll 8
  for (int t = 0; t < 64; t++) dh0 += W1m[k*64 + t] * d1[t];
  dz0[m*64 + k] = (a0 > 0.f) ? dh0 : 0.f;
}

// ---------------- K5: g[m][j] = (W0[m][j][:] . dz0[m]) * gamma[j]; LN-bwd sums ----------------
__global__ void k_bwdx(const float4* __restrict__ W0, const float* __restrict__ gamma,
                       float* __restrict__ ws) {
  int m = blockIdx.y;
  __shared__ float4 dz[16];
  if (threadIdx.x < 16) dz[threadIdx.x] = ((const float4*)(ws + WS_DZ0))[m*16 + threadIdx.x];
  __syncthreads();
  float mu  = ws[WS_SUMS + 0] * (1.f / NX);
  float var = ws[WS_SUMS + 1] * (1.f / NX) - mu * mu;
  float inv = 1.f / sqrtf(var + LN_EPSF);
  int j = blockIdx.x * blockDim.x + threadIdx.x;
  float sg = 0.f, sgx = 0.f;
  if (j < NX) {
    const float4* row = W0 + ((size_t)m * NX + j) * 16;
    float dot = 0.f;
    #pragma unroll
    for (int c = 0; c < 16; c++) {
      float4 wv = row[c];
      float4 d  = dz[c];
      dot += wv.x*d.x + wv.y*d.y + wv.z*d.z + wv.w*d.w;
    }
    float gg = dot * gamma[j];
    ws[WS_G + (size_t)m * NX + j] = gg;
    float xh = (ws[WS_XRAW + j] - mu) * inv;
    sg = gg; sgx = gg * xh;
  }
  block_sum2(sg, sgx, ws + WS_SG + m, ws + WS_SGX + m);
}

// ---------------- K6: per-CV mean force + model variance ----------------
__global__ void k_mf(float* __restrict__ ws) {
  int i = blockIdx.x * blockDim.x + threadIdx.x;
  float v = 0.f;
  if (i < NCV) {
    float mu  = ws[WS_SUMS + 0] * (1.f / NX);
    float var = ws[WS_SUMS + 1] * (1.f / NX) - mu * mu;
    float inv = 1.f / sqrtf(var + LN_EPSF);
    float c = ws[WS_XRAW + i], s = ws[WS_XRAW + NCV + i];
    float xc = (c - mu) * inv, xs = (s - mu) * inv;
    float f[NM];
    float fm = 0.f;
    #pragma unroll
    for (int m = 0; m < NM; m++) {
      float gc = ws[WS_G + (size_t)m * NX + i];
      float gs = ws[WS_G + (size_t)m * NX + NCV + i];
      float Sg  = ws[WS_SG + m]  * (1.f / NX);
      float Sgx = ws[WS_SGX + m] * (1.f / NX);
      float dxc = inv * (gc - Sg - xc * Sgx);
      float dxs = inv * (gs - Sg - xs * Sgx);
      float dE = dxc * (-s) + dxs * c;   // d cos = -sin, d sin = cos
      f[m] = -dE;
      fm += f[m];
    }
    fm *= (1.f / NM);
    ws[WS_MF + i] = fm;
    float acc = 0.f;
    #pragma unroll
    for (int m = 0; m < NM; m++) { float d = f[m] - fm; acc += d * d; }
    v = acc * (1.f / (NM - 1));          // ddof=1
  }
  block_sum1(v, ws + WS_VARSUM);
}

// ---------------- K7: sigma + energy scalar ----------------
__global__ void k_sigma(float* __restrict__ ws, float* __restrict__ dout) {
  if (threadIdx.x == 0 && blockIdx.x == 0) {
    float md = sqrtf(ws[WS_VARSUM] * (1.f / NCV));
    float isw = (3.0f - md) / (3.0f - 2.0f);
    float fl = floorf(isw);
    float smooth = 0.5f * (1.f + cosf(3.14159265358979323846f * (1.f - isw)));
    float sigma = (fl > 0.f) ? 1.f : ((fl < 0.f) ? 0.f : smooth);
    float em = 0.f;
    #pragma unroll
    for (int m = 0; m < NM; m++) em += ws[WS_E + m];
    em *= (1.f / NM);
    dout[0] = em * sigma;
    ws[WS_SIGMA] = sigma;
  }
}

// ---------------- K8: scatter forces ----------------
__global__ void k_scatter(const int* __restrict__ idx, const float* __restrict__ ws,
                          float* __restrict__ forces) {
  int t = blockIdx.x * blockDim.x + threadIdx.x;
  if (t >= NCV * 12) return;
  int i = t / 12, r = t - i * 12;
  int a = r / 3, d = r - a * 3;
  float sigma = ws[WS_SIGMA];
  float contrib = ws[WS_MF + i] * ws[WS_DCV + (size_t)i * 12 + r] * sigma;
  atomicAdd(&forces[(size_t)idx[i*4 + a] * 3 + d], contrib);
}

extern "C" void kernel_launch(void* const* d_in, const int* in_sizes, int n_in,
                              void* d_out, int out_size, void* d_ws, size_t ws_size,
                              hipStream_t stream) {
  const float* pos   = (const float*)d_in[0];
  const float* box   = (const float*)d_in[1];
  const int*   idx   = (const int*)  d_in[2];
  const float* gamma = (const float*)d_in[3];
  const float* beta  = (const float*)d_in[4];
  const float* W0 = (const float*)d_in[5];
  const float* b0 = (const float*)d_in[6];
  const float* W1 = (const float*)d_in[7];
  const float* b1 = (const float*)d_in[8];
  const float* W2 = (const float*)d_in[9];
  const float* b2 = (const float*)d_in[10];
  const float* W3 = (const float*)d_in[11];
  const float* b3 = (const float*)d_in[12];
  const float* W4 = (const float*)d_in[13];
  const float* b4 = (const float*)d_in[14];
  float* ws  = (float*)d_ws;
  float* out = (float*)d_out;

  // zero outputs + accumulators (ws/d_out are poisoned, never re-poisoned)
  hipMemsetAsync(d_out, 0, (size_t)out_size * sizeof(float), stream);
  hipMemsetAsync(ws + WS_Z0, 0, (size_t)(WS_TOTAL - WS_Z0) * sizeof(float), stream);

  k_cv<<<(NCV + 255) / 256, 256, 0, stream>>>(pos, box, idx, ws);
  k_y<<<(NX + 255) / 256, 256, 0, stream>>>(gamma, beta, ws);
  k_z0<<<dim3((NX + 1023) / 1024, NM), 256, 0, stream>>>((const float4*)W0, ws + WS_Y, ws + WS_Z0);
  k_mlp<<<NM, 64, 0, stream>>>(ws + WS_Z0, b0, W1, b1, W2, b2, W3, b3, W4, b4,
                               ws + WS_DZ0, ws + WS_E);
  k_bwdx<<<dim3((NX + 255) / 256, NM), 256, 0, stream>>>((const float4*)W0, gamma, ws);
  k_mf<<<(NCV + 255) / 256, 256, 0, stream>>>(ws);
  k_sigma<<<1, 64, 0, stream>>>(ws, out);
  k_scatter<<<(NCV * 12 + 255) / 256, 256, 0, stream>>>(idx, ws, out + 1);
}

// Round 2
// 95.225 us; speedup vs baseline: 1.3943x; 1.3943x over previous
//
#include <hip/hip_runtime.h>
#include <math.h>

#define NCV   30000
#define NX    60000
#define NM    8
#define LN_EPSF 1e-5f
#define NFORCE 9000000      // force floats (3M x 3); d_out = [energy, forces...]

#define NB_CV 512           // k_cv grid
#define JB    59            // k_z0 j-blocks of 1024
#define NBX   235           // k_bwdx blocks per model (256 rows each)
#define NB_MF 118           // k_mf grid

// ---------------- workspace layout (float offsets) ----------------
#define WS_XRAW   0          // 60000  (cos | sin)
#define WS_DCV    60000      // 360000 dphi/dx (30000 x 12)
#define WS_G      420000     // 480000 dE/dxhat per model (8 x 60000)
#define WS_MF     900000     // 30000
#define WS_LNP    930000     // 1024: [512 sum_x | 512 sum_x2] per-block partials
#define WS_Z0P    931024     // 8*59*64 z0 partials
#define WS_DZ0    961232     // 512
#define WS_E      961744     // 8
#define WS_SGP    961752     // 8*235
#define WS_SGXP   963632     // 8*235
#define WS_VARSUM 965512     // 1
#define WS_TICKET 965513     // 1 (uint bits)
#define WS_SIGMA  965514     // 1

struct F3 { float x, y, z; };
__device__ __forceinline__ F3 f3sub(F3 a, F3 b){ return {a.x-b.x, a.y-b.y, a.z-b.z}; }
__device__ __forceinline__ F3 f3add(F3 a, F3 b){ return {a.x+b.x, a.y+b.y, a.z+b.z}; }
__device__ __forceinline__ F3 f3scale(F3 a, float s){ return {a.x*s, a.y*s, a.z*s}; }
__device__ __forceinline__ float f3dot(F3 a, F3 b){ return a.x*b.x + a.y*b.y + a.z*b.z; }
__device__ __forceinline__ F3 f3cross(F3 a, F3 b){
  return { a.y*b.z - a.z*b.y, a.z*b.x - a.x*b.z, a.x*b.y - a.y*b.x };
}

// reduce LN per-block partials -> out2[0]=mu, out2[1]=inv_std  (wave 0 only; caller syncs)
__device__ __forceinline__ void compute_mu_inv(const float* __restrict__ ws, float* out2, int tid) {
  if (tid < 64) {
    float a = 0.f, b = 0.f;
    #pragma unroll 4
    for (int k = tid; k < NB_CV; k += 64) { a += ws[WS_LNP + k]; b += ws[WS_LNP + NB_CV + k]; }
    #pragma unroll
    for (int o = 1; o < 64; o <<= 1) { a += __shfl_xor(a, o); b += __shfl_xor(b, o); }
    if (tid == 0) {
      float mu  = a * (1.f / NX);
      float var = b * (1.f / NX) - mu * mu;
      out2[0] = mu;
      out2[1] = 1.f / sqrtf(var + LN_EPSF);
    }
  }
}

// ---------------- K1: dihedrals + grads + LN stat partials + zero forces ----------------
__global__ void k_cv(const float* __restrict__ pos, const float* __restrict__ box,
                     const int* __restrict__ idx, float* __restrict__ ws,
                     float* __restrict__ out) {
  int tid = threadIdx.x;
  int gtid = blockIdx.x * 256 + tid;

  // zero forces (grid-stride float4); out+1..out+NFORCE, aligned part starts at out+4
  {
    float4 z4 = {0.f, 0.f, 0.f, 0.f};
    float4* fz = (float4*)(out + 4);
    const int NF4 = (NFORCE - 4) / 4;   // floats 4..8999999
    for (int i = gtid; i < NF4; i += NB_CV * 256) fz[i] = z4;
    if (gtid == 0) {
      out[1] = 0.f; out[2] = 0.f; out[3] = 0.f; out[NFORCE] = 0.f;
      ws[WS_VARSUM] = 0.f; ws[WS_TICKET] = 0.f;
    }
  }

  float cx = 0.f, cx2 = 0.f;
  int i = gtid;
  if (i < NCV) {
    float bx = box[0], by = box[4], bz = box[8];
    F3 p[4];
    #pragma unroll
    for (int a = 0; a < 4; a++) {
      int pi = idx[i*4 + a];
      float X = pos[(size_t)pi*3 + 0];
      float Y = pos[(size_t)pi*3 + 1];
      float Z = pos[(size_t)pi*3 + 2];
      X -= floorf(X / bx) * bx;
      Y -= floorf(Y / by) * by;
      Z -= floorf(Z / bz) * bz;
      p[a] = {X, Y, Z};
    }
    F3 b1 = f3sub(p[1], p[0]);
    F3 b2 = f3sub(p[2], p[1]);
    F3 b3 = f3sub(p[3], p[2]);
    F3 n1 = f3cross(b1, b2);
    F3 n2 = f3cross(b2, b3);
    float L = sqrtf(f3dot(b2, b2));
    F3 u = f3scale(b2, 1.f / L);
    F3 m1 = f3cross(n1, u);
    float yv = f3dot(m1, n2);
    float xv = f3dot(n1, n2);
    float h = sqrtf(xv*xv + yv*yv);
    float cphi = xv / h;
    float sphi = yv / h;

    // reverse mode, dphi = 1
    float invd = 1.f / (h*h);
    float dX = -yv * invd;
    float dY =  xv * invd;
    F3 dn1 = f3scale(n2, dX);
    F3 dn2 = f3scale(n1, dX);
    F3 dm1 = f3scale(n2, dY);
    dn2 = f3add(dn2, f3scale(m1, dY));
    dn1 = f3add(dn1, f3cross(u, dm1));
    F3 du = f3cross(dm1, n1);
    float ud = f3dot(u, du);
    F3 db2 = f3scale(f3sub(du, f3scale(u, ud)), 1.f / L);
    db2 = f3add(db2, f3cross(b3, dn2));
    F3 db3 = f3cross(dn2, b2);
    F3 db1 = f3cross(b2, dn1);
    db2 = f3add(db2, f3cross(dn1, b1));

    F3 g0 = f3scale(db1, -1.f);
    F3 g1 = f3sub(db1, db2);
    F3 g2 = f3sub(db2, db3);
    F3 g3 = db3;

    ws[WS_XRAW + i]       = cphi;
    ws[WS_XRAW + NCV + i] = sphi;
    float* dc = ws + WS_DCV + (size_t)i * 12;
    dc[0] = g0.x; dc[1]  = g0.y; dc[2]  = g0.z;
    dc[3] = g1.x; dc[4]  = g1.y; dc[5]  = g1.z;
    dc[6] = g2.x; dc[7]  = g2.y; dc[8]  = g2.z;
    dc[9] = g3.x; dc[10] = g3.y; dc[11] = g3.z;

    cx  = cphi + sphi;
    cx2 = cphi*cphi + sphi*sphi;
  }

  // block-reduce (cx, cx2) -> direct per-block partial store (no atomics)
  #pragma unroll
  for (int o = 1; o < 64; o <<= 1) { cx += __shfl_xor(cx, o); cx2 += __shfl_xor(cx2, o); }
  __shared__ float sa[4], sb[4];
  int w = tid >> 6, l = tid & 63;
  if (l == 0) { sa[w] = cx; sb[w] = cx2; }
  __syncthreads();
  if (tid == 0) {
    ws[WS_LNP + blockIdx.x]         = sa[0] + sa[1] + sa[2] + sa[3];
    ws[WS_LNP + NB_CV + blockIdx.x] = sb[0] + sb[1] + sb[2] + sb[3];
  }
}

// ---------------- K2: z0 partials; y computed in-block ----------------
__global__ void k_z0(const float4* __restrict__ W0, const float* __restrict__ gamma,
                     const float* __restrict__ beta, float* __restrict__ ws) {
  __shared__ float stats[2];
  __shared__ float yl[1024];
  __shared__ float red[4][16][4];
  int tid = threadIdx.x;
  int jb = blockIdx.x, m = blockIdx.y;
  int j0 = jb * 1024;
  int jcount = min(1024, NX - j0);

  compute_mu_inv(ws, stats, tid);
  __syncthreads();
  float mu = stats[0], inv = stats[1];
  for (int jj = tid; jj < 1024; jj += 256) {
    int gj = j0 + jj;
    yl[jj] = (gj < NX) ? ((ws[WS_XRAW + gj] - mu) * inv * gamma[gj] + beta[gj]) : 0.f;
  }
  __syncthreads();

  int k4 = tid & 15;     // float4 column of the 64-wide row
  int r  = tid >> 4;     // row phase 0..15
  const float4* Wm = W0 + (size_t)m * NX * 16;
  float4 acc = {0.f, 0.f, 0.f, 0.f};
  #pragma unroll 4
  for (int j = r; j < jcount; j += 16) {
    float y = yl[j];
    float4 wv = Wm[(size_t)(j0 + j) * 16 + k4];
    acc.x += y * wv.x; acc.y += y * wv.y; acc.z += y * wv.z; acc.w += y * wv.w;
  }
  #pragma unroll
  for (int o = 16; o <= 32; o <<= 1) {
    acc.x += __shfl_xor(acc.x, o); acc.y += __shfl_xor(acc.y, o);
    acc.z += __shfl_xor(acc.z, o); acc.w += __shfl_xor(acc.w, o);
  }
  int w = tid >> 6, l = tid & 63;
  if (l < 16) {
    red[w][l][0] = acc.x; red[w][l][1] = acc.y; red[w][l][2] = acc.z; red[w][l][3] = acc.w;
  }
  __syncthreads();
  if (tid < 64) {
    int kk4 = tid & 15, c = tid >> 4;
    float v = red[0][kk4][c] + red[1][kk4][c] + red[2][kk4][c] + red[3][kk4][c];
    ws[WS_Z0P + ((size_t)m * JB + jb) * 64 + kk4 * 4 + c] = v;   // direct store
  }
}

// ---------------- K3: tiny MLP fwd+bwd per model (reduces z0 partials) ----------------
__global__ void k_mlp(const float* __restrict__ ws_ro, const float* __restrict__ b0,
                      const float* __restrict__ W1, const float* __restrict__ b1,
                      const float* __restrict__ W2, const float* __restrict__ b2,
                      const float* __restrict__ W3, const float* __restrict__ b3,
                      const float* __restrict__ W4, const float* __restrict__ b4,
                      float* __restrict__ ws) {
  int m = blockIdx.x, k = threadIdx.x;   // 64 threads
  __shared__ float h0[64], h1[64], h2[64], d3[64], d2[64], d1[64];
  const float* W1m = W1 + m * 4096;
  const float* W2m = W2 + m * 4096;
  const float* W3m = W3 + m * 4096;

  float a0 = b0[m*64 + k];
  #pragma unroll 4
  for (int jb = 0; jb < JB; jb++) a0 += ws_ro[WS_Z0P + ((size_t)m * JB + jb) * 64 + k];
  h0[k] = fmaxf(a0, 0.f);
  __syncthreads();
  float a1 = b1[m*64 + k];
  #pragma unroll 8
  for (int t = 0; t < 64; t++) a1 += h0[t] * W1m[t*64 + k];
  h1[k] = fmaxf(a1, 0.f);
  __syncthreads();
  float a2 = b2[m*64 + k];
  #pragma unroll 8
  for (int t = 0; t < 64; t++) a2 += h1[t] * W2m[t*64 + k];
  h2[k] = fmaxf(a2, 0.f);
  __syncthreads();
  float a3 = b3[m*64 + k];
  #pragma unroll 8
  for (int t = 0; t < 64; t++) a3 += h2[t] * W3m[t*64 + k];
  float h3 = fmaxf(a3, 0.f);

  float w4 = W4[m*64 + k];
  float e = h3 * w4;
  #pragma unroll
  for (int o = 1; o < 64; o <<= 1) e += __shfl_xor(e, o);
  if (k == 0) ws[WS_E + m] = e + b4[m];

  float dz3 = (a3 > 0.f) ? w4 : 0.f;
  d3[k] = dz3;
  __syncthreads();
  float dh2 = 0.f;
  #pragma unroll 8
  for (int t = 0; t < 64; t++) dh2 += W3m[k*64 + t] * d3[t];
  float dz2 = (a2 > 0.f) ? dh2 : 0.f;
  d2[k] = dz2;
  __syncthreads();
  float dh1 = 0.f;
  #pragma unroll 8
  for (int t = 0; t < 64; t++) dh1 += W2m[k*64 + t] * d2[t];
  float dz1 = (a1 > 0.f) ? dh1 : 0.f;
  d1[k] = dz1;
  __syncthreads();
  float dh0 = 0.f;
  #pragma unroll 8
  for (int t = 0; t < 64; t++) dh0 += W1m[k*64 + t] * d1[t];
  ws[WS_DZ0 + m*64 + k] = (a0 > 0.f) ? dh0 : 0.f;
}

// ---------------- K4: g[m][j] = (W0[m][j][:].dz0[m])*gamma[j]; coalesced 16-lane/row ----------------
__global__ void k_bwdx(const float4* __restrict__ W0, const float* __restrict__ gamma,
                       float* __restrict__ ws) {
  __shared__ float stats[2];
  __shared__ float dz[64];
  __shared__ float sa[4], sb[4];
  int tid = threadIdx.x;
  int m = blockIdx.y, blk = blockIdx.x;

  compute_mu_inv(ws, stats, tid);
  if (tid >= 64 && tid < 128) dz[tid - 64] = ws[WS_DZ0 + m*64 + (tid - 64)];
  __syncthreads();
  float mu = stats[0], inv = stats[1];

  int c = tid & 15;        // float4 column within row
  int g = tid >> 4;        // row group 0..15
  const float4* dz4 = (const float4*)dz;
  float4 d4 = dz4[c];

  float sg = 0.f, sgx = 0.f;
  #pragma unroll 2
  for (int it = 0; it < 16; it++) {
    int j = blk * 256 + it * 16 + g;
    if (j < NX) {
      float4 wv = W0[((size_t)m * NX + j) * 16 + c];
      float dot = wv.x*d4.x + wv.y*d4.y + wv.z*d4.z + wv.w*d4.w;
      #pragma unroll
      for (int o = 1; o < 16; o <<= 1) dot += __shfl_xor(dot, o);
      if (c == 0) {
        float gg = dot * gamma[j];
        ws[WS_G + (size_t)m * NX + j] = gg;
        float xh = (ws[WS_XRAW + j] - mu) * inv;
        sg += gg; sgx += gg * xh;
      }
    }
  }
  // block-reduce sg/sgx -> per-block partial store
  #pragma unroll
  for (int o = 1; o < 64; o <<= 1) { sg += __shfl_xor(sg, o); sgx += __shfl_xor(sgx, o); }
  int w = tid >> 6, l = tid & 63;
  if (l == 0) { sa[w] = sg; sb[w] = sgx; }
  __syncthreads();
  if (tid == 0) {
    ws[WS_SGP  + m * NBX + blk] = sa[0] + sa[1] + sa[2] + sa[3];
    ws[WS_SGXP + m * NBX + blk] = sb[0] + sb[1] + sb[2] + sb[3];
  }
}

// ---------------- K5: mean force + variance; last block does sigma + energy ----------------
__global__ void k_mf(float* __restrict__ ws, float* __restrict__ out) {
  __shared__ float stats[2];
  __shared__ float sSg[NM], sSgx[NM];
  __shared__ float sv[4];
  int tid = threadIdx.x;
  int w = tid >> 6, l = tid & 63;

  compute_mu_inv(ws, stats, tid);
  // wave w reduces models w and w+4
  for (int m = w; m < NM; m += 4) {
    float a = 0.f, b = 0.f;
    #pragma unroll 2
    for (int bb = l; bb < NBX; bb += 64) { a += ws[WS_SGP + m*NBX + bb]; b += ws[WS_SGXP + m*NBX + bb]; }
    #pragma unroll
    for (int o = 1; o < 64; o <<= 1) { a += __shfl_xor(a, o); b += __shfl_xor(b, o); }
    if (l == 0) { sSg[m] = a * (1.f / NX); sSgx[m] = b * (1.f / NX); }
  }
  __syncthreads();
  float mu = stats[0], inv = stats[1];

  int i = blockIdx.x * 256 + tid;
  float v = 0.f;
  if (i < NCV) {
    float cph = ws[WS_XRAW + i], sph = ws[WS_XRAW + NCV + i];
    float xc = (cph - mu) * inv, xs = (sph - mu) * inv;
    float f[NM];
    float fm = 0.f;
    #pragma unroll
    for (int m = 0; m < NM; m++) {
      float gc = ws[WS_G + (size_t)m * NX + i];
      float gs = ws[WS_G + (size_t)m * NX + NCV + i];
      float dxc = inv * (gc - sSg[m] - xc * sSgx[m]);
      float dxs = inv * (gs - sSg[m] - xs * sSgx[m]);
      float dE = dxc * (-sph) + dxs * cph;
      f[m] = -dE;
      fm += f[m];
    }
    fm *= (1.f / NM);
    ws[WS_MF + i] = fm;
    float acc = 0.f;
    #pragma unroll
    for (int m = 0; m < NM; m++) { float d = f[m] - fm; acc += d * d; }
    v = acc * (1.f / (NM - 1));
  }
  #pragma unroll
  for (int o = 1; o < 64; o <<= 1) v += __shfl_xor(v, o);
  if (l == 0) sv[w] = v;
  __syncthreads();
  if (tid == 0) {
    atomicAdd(&ws[WS_VARSUM], sv[0] + sv[1] + sv[2] + sv[3]);
    __threadfence();
    unsigned int* tick = (unsigned int*)&ws[WS_TICKET];
    unsigned int old = atomicAdd(tick, 1u);
    if (old == NB_MF - 1) {
      __threadfence();
      float tot = atomicAdd(&ws[WS_VARSUM], 0.0f);   // coherent read
      float md = sqrtf(tot * (1.f / NCV));
      float isw = (3.0f - md) / (3.0f - 2.0f);
      float fl = floorf(isw);
      float smooth = 0.5f * (1.f + cosf(3.14159265358979323846f * (1.f - isw)));
      float sigma = (fl > 0.f) ? 1.f : ((fl < 0.f) ? 0.f : smooth);
      float em = 0.f;
      #pragma unroll
      for (int m = 0; m < NM; m++) em += ws[WS_E + m];
      em *= (1.f / NM);
      out[0] = em * sigma;
      ws[WS_SIGMA] = sigma;
    }
  }
}

// ---------------- K6: scatter forces ----------------
__global__ void k_scatter(const int* __restrict__ idx, const float* __restrict__ ws,
                          float* __restrict__ forces) {
  int t = blockIdx.x * blockDim.x + threadIdx.x;
  if (t >= NCV * 12) return;
  int i = t / 12, r = t - i * 12;
  int a = r / 3, d = r - a * 3;
  float sigma = ws[WS_SIGMA];
  float contrib = ws[WS_MF + i] * ws[WS_DCV + (size_t)i * 12 + r] * sigma;
  atomicAdd(&forces[(size_t)idx[i*4 + a] * 3 + d], contrib);
}

extern "C" void kernel_launch(void* const* d_in, const int* in_sizes, int n_in,
                              void* d_out, int out_size, void* d_ws, size_t ws_size,
                              hipStream_t stream) {
  const float* pos   = (const float*)d_in[0];
  const float* box   = (const float*)d_in[1];
  const int*   idx   = (const int*)  d_in[2];
  const float* gamma = (const float*)d_in[3];
  const float* beta  = (const float*)d_in[4];
  const float* W0 = (const float*)d_in[5];
  const float* b0 = (const float*)d_in[6];
  const float* W1 = (const float*)d_in[7];
  const float* b1 = (const float*)d_in[8];
  const float* W2 = (const float*)d_in[9];
  const float* b2 = (const float*)d_in[10];
  const float* W3 = (const float*)d_in[11];
  const float* b3 = (const float*)d_in[12];
  const float* W4 = (const float*)d_in[13];
  const float* b4 = (const float*)d_in[14];
  float* ws  = (float*)d_ws;
  float* out = (float*)d_out;

  k_cv<<<NB_CV, 256, 0, stream>>>(pos, box, idx, ws, out);
  k_z0<<<dim3(JB, NM), 256, 0, stream>>>((const float4*)W0, gamma, beta, ws);
  k_mlp<<<NM, 64, 0, stream>>>(ws, b0, W1, b1, W2, b2, W3, b3, W4, b4, ws);
  k_bwdx<<<dim3(NBX, NM), 256, 0, stream>>>((const float4*)W0, gamma, ws);
  k_mf<<<NB_MF, 256, 0, stream>>>(ws, out);
  k_scatter<<<(NCV * 12 + 255) / 256, 256, 0, stream>>>(idx, ws, out + 1);
}